// Round 13
// baseline (536.200 us; speedup 1.0000x reference)
//
#include <hip/hip_runtime.h>
#include <hip/hip_bf16.h>
#include <math.h>

// Swin block, MI355X. f32 inputs -> f32 output. B=8, H=W=64, C=512, HEADS=16,
// WS=8, SHIFT=4, N=64 tok/window, NW=64, HEAD_DIM=32, HIDDEN=2048, M=32768.
// Round 13: r12 with the gemmsk grid fix: 2048 blocks = 4 kslices x 512 tiles
// (128 m-blocks x 4 n-blocks). r12 launched 1024 and dropped half the rows.

typedef unsigned short ushort_t;
typedef __attribute__((ext_vector_type(8))) short short8;
typedef __attribute__((ext_vector_type(8))) __bf16 bf16x8;
typedef __attribute__((ext_vector_type(4))) float f32x4;

#define DEVINL __device__ __forceinline__

union frag_u { short8 s; bf16x8 b; };

DEVINL float bf2f(ushort_t u){ union {unsigned int i; float f;} c; c.i = ((unsigned)u)<<16; return c.f; }
DEVINL ushort_t f2bf(float f){ union {unsigned int i; float f;} c; c.f = f; unsigned r = c.i + 0x7fffu + ((c.i>>16)&1u); return (ushort_t)(r>>16); }

typedef const __attribute__((address_space(1))) void* gas_t;
typedef __attribute__((address_space(3))) void* las_t;
DEVINL void load_lds16(const void* g, void* l) {
  __builtin_amdgcn_global_load_lds((gas_t)g, (las_t)l, 16, 0, 0);
}

// exact-GELU via Abramowitz-Stegun 7.1.25 erf (|err| <= 2.5e-5; bf16-invisible)
DEVINL float gelu_fast(float v){
  float z  = fabsf(v) * 0.70710678118654752f;
  float t  = __builtin_amdgcn_rcpf(fmaf(0.47047f, z, 1.0f));
  float p  = t * fmaf(t, fmaf(t, 0.7478556f, -0.0958798f), 0.3480242f);
  float e  = __expf(-z*z);
  float er = fmaf(-p, e, 1.0f);                 // erf(z), z>=0
  float hs = (v >= 0.f) ? 0.5f : -0.5f;
  return v * fmaf(hs, er, 0.5f);
}

// window-order token t -> source/dest row in [B, H*W] (includes the ±SHIFT roll)
DEVINL int win_map_row(int t){
  int bw = t >> 6, n = t & 63;
  int b  = bw >> 6, wdx = bw & 63;
  int wh = wdx >> 3, ww = wdx & 7;
  int r  = n >> 3,  c  = n & 7;
  int hh = (wh*8 + r + 4) & 63;
  int w2 = (ww*8 + c + 4) & 63;
  return (b << 12) + (hh << 6) + w2;
}

// XCD-chunked bijective block remap (nwg % 8 == 0), n-fastest logical order
DEVINL void remap_mn(int bid, int nwg, int nbn, int BM, int BN, int& m0, int& n0){
  int q    = nwg >> 3;
  int lbid = (bid & 7)*q + (bid >> 3);
  m0 = (lbid / nbn) * BM;
  n0 = (lbid % nbn) * BN;
}

// ---------------- merged transpose: 4 weights f32 -> bf16 B^T layout ----------------
__global__ void transpose_all(const float* __restrict__ qkv_w, const float* __restrict__ proj_w,
                              const float* __restrict__ fc1_w, const float* __restrict__ fc2_w,
                              ushort_t* __restrict__ wqT, ushort_t* __restrict__ wpT,
                              ushort_t* __restrict__ w1T, ushort_t* __restrict__ w2T){
  __shared__ float t[32][33];
  int bid = blockIdx.x;
  const float* in; ushort_t* out; int R, Ccols, bx, by;
  if (bid < 768)      { in=qkv_w;  out=wqT; R=512;  Ccols=1536; bx=(bid%48)*32;        by=(bid/48)*32; }
  else if (bid < 1024){ int b=bid-768;  in=proj_w; out=wpT; R=512;  Ccols=512;  bx=(b%16)*32; by=(b/16)*32; }
  else if (bid < 2048){ int b=bid-1024; in=fc1_w;  out=w1T; R=512;  Ccols=2048; bx=(b%64)*32; by=(b/64)*32; }
  else                { int b=bid-2048; in=fc2_w;  out=w2T; R=2048; Ccols=512;  bx=(b%16)*32; by=(b/16)*32; }
  int x = threadIdx.x, y = threadIdx.y;
  #pragma unroll
  for (int i=0;i<32;i+=8) t[y+i][x] = in[(size_t)(by+y+i)*Ccols + bx + x];
  __syncthreads();
  #pragma unroll
  for (int i=0;i<32;i+=8) out[(size_t)(bx+y+i)*R + by + x] = f2bf(t[x][y+i]);
}

// ---------------- LayerNorm f32-in, bf16-out (optional shift+window gather) ----------------
__global__ __launch_bounds__(256) void ln_kernel(const float* __restrict__ in,
    const float* __restrict__ g, const float* __restrict__ bta,
    ushort_t* __restrict__ out, int windowed){
  int tid = threadIdx.x; int l = tid & 63; int w = tid >> 6;
  int t = blockIdx.x * 4 + w;
  int src = windowed ? win_map_row(t) : t;
  const float* row = in + (size_t)src * 512;
  float4 v0 = *(const float4*)(row + l*8);
  float4 v1 = *(const float4*)(row + l*8 + 4);
  float f[8] = {v0.x,v0.y,v0.z,v0.w, v1.x,v1.y,v1.z,v1.w};
  float s=0.f, s2=0.f;
  #pragma unroll
  for (int j=0;j<8;j++){ s += f[j]; s2 += f[j]*f[j]; }
  #pragma unroll
  for (int m=1;m<64;m<<=1){ s += __shfl_xor(s,m); s2 += __shfl_xor(s2,m); }
  float mu  = s * (1.f/512.f);
  float var = s2*(1.f/512.f) - mu*mu;
  float rs  = rsqrtf(var + 1e-3f);
  float4 g0 = *(const float4*)(g + l*8),   g1 = *(const float4*)(g + l*8 + 4);
  float4 b0 = *(const float4*)(bta + l*8), b1 = *(const float4*)(bta + l*8 + 4);
  float gg[8] = {g0.x,g0.y,g0.z,g0.w, g1.x,g1.y,g1.z,g1.w};
  float bb[8] = {b0.x,b0.y,b0.z,b0.w, b1.x,b1.y,b1.z,b1.w};
  short8 o;
  #pragma unroll
  for (int j=0;j<8;j++) o[j] = (short)f2bf((f[j]-mu)*rs*gg[j] + bb[j]);
  *(short8*)(out + (size_t)t*512 + l*8) = o;
}

// ---------------- GEMM 256x256, BK=64, 8 waves, 8-phase counted-vmcnt ----------------
// EPI 0: bf16 short8 store; 2: f32 float4 scatter out[win_map_row] = xres + v.
#define G_STAGE(G, base, h, tt, LB) do { \
    load_lds16((G) + (base) + (size_t)((h)*128)*K    + (size_t)(tt)*64, &lds[(LB) + (h)*8192 +        w*512]); \
    load_lds16((G) + (base) + (size_t)((h)*128+64)*K + (size_t)(tt)*64, &lds[(LB) + (h)*8192 + 4096 + w*512]); \
  } while(0)

#define NOWAIT
#define VM4 asm volatile("s_waitcnt vmcnt(4)" ::: "memory")

#define PHASE(mp, STAGE_STMT, EXTRA) do { \
    bf16x8 a0 = *(const bf16x8*)&lds[ALb + aoff[2*(mp)  ][0]]; \
    bf16x8 a1 = *(const bf16x8*)&lds[ALb + aoff[2*(mp)  ][1]]; \
    bf16x8 a2 = *(const bf16x8*)&lds[ALb + aoff[2*(mp)+1][0]]; \
    bf16x8 a3 = *(const bf16x8*)&lds[ALb + aoff[2*(mp)+1][1]]; \
    STAGE_STMT; \
    EXTRA; \
    __builtin_amdgcn_s_barrier(); \
    asm volatile("s_waitcnt lgkmcnt(0)" ::: "memory"); \
    __builtin_amdgcn_sched_barrier(0); \
    __builtin_amdgcn_s_setprio(1); \
    _Pragma("unroll") \
    for (int nf=0; nf<4; nf++){ \
      acc[2*(mp)  ][nf] = __builtin_amdgcn_mfma_f32_16x16x32_bf16(a0, bfr[nf][0], acc[2*(mp)  ][nf], 0,0,0); \
      acc[2*(mp)  ][nf] = __builtin_amdgcn_mfma_f32_16x16x32_bf16(a1, bfr[nf][1], acc[2*(mp)  ][nf], 0,0,0); \
      acc[2*(mp)+1][nf] = __builtin_amdgcn_mfma_f32_16x16x32_bf16(a2, bfr[nf][0], acc[2*(mp)+1][nf], 0,0,0); \
      acc[2*(mp)+1][nf] = __builtin_amdgcn_mfma_f32_16x16x32_bf16(a3, bfr[nf][1], acc[2*(mp)+1][nf], 0,0,0); \
    } \
    __builtin_amdgcn_s_setprio(0); \
    __builtin_amdgcn_sched_barrier(0); \
    __builtin_amdgcn_s_barrier(); \
  } while(0)

template<int EPI>
__global__ __launch_bounds__(512, 2) void gemm256(
    const ushort_t* __restrict__ A, const ushort_t* __restrict__ Bt,
    const float* __restrict__ bias, void* __restrict__ Cout_v,
    const float* __restrict__ xres, int M, int N, int K, int nbn)
{
  __shared__ ushort_t lds[65536];   // 128 KiB: 2 bufs x (A 32KB + B 32KB)
  const int tid = threadIdx.x; const int l = tid & 63; const int w = tid >> 6;
  const int wm = w >> 2, wn = w & 3;
  int m0, n0;
  remap_mn(blockIdx.x, gridDim.x, nbn, 256, 256, m0, n0);
  const int lr = l & 15, lk = l >> 4;
  const int nt = K >> 6;                 // K-tiles of 64

  const int r0 = tid >> 3;
  const int kc = ((tid & 7) - r0) & 7;
  const size_t aRow0 = (size_t)(m0 + r0) * K + kc * 8;
  const size_t bRow0 = (size_t)(n0 + r0) * K + kc * 8;

  int aoff[8][2], boff[4][2];
  #pragma unroll
  for (int mf=0; mf<8; mf++){
    int row = wm*128 + mf*16 + lr;
    #pragma unroll
    for (int kh=0; kh<2; kh++){ int c = kh*4 + lk; aoff[mf][kh] = (row*8 + ((c + row)&7))*8; }
  }
  #pragma unroll
  for (int nf=0; nf<4; nf++){
    int row = wn*64 + nf*16 + lr;
    #pragma unroll
    for (int kh=0; kh<2; kh++){ int c = kh*4 + lk; boff[nf][kh] = (row*8 + ((c + row)&7))*8; }
  }

  f32x4 acc[8][4] = {};

  G_STAGE(A,  aRow0, 0, 0, 0);
  G_STAGE(A,  aRow0, 1, 0, 0);
  G_STAGE(Bt, bRow0, 0, 0, 16384);
  G_STAGE(Bt, bRow0, 1, 0, 16384);
  G_STAGE(Bt, bRow0, 0, 1, 32768+16384);
  G_STAGE(Bt, bRow0, 1, 1, 32768+16384);
  VM4;
  __builtin_amdgcn_s_barrier();

  for (int t = 0; t < nt; ++t) {
    const int b   = t & 1;
    const int ALb = b*32768, BLb = ALb + 16384;
    const int ALn = (b^1)*32768;
    const int t1  = (t+1 < nt) ? t+1 : t;
    const int t2  = (t+2 < nt) ? t+2 : t;

    bf16x8 bfr[4][2];
    #pragma unroll
    for (int nf=0; nf<4; nf++){
      bfr[nf][0] = *(const bf16x8*)&lds[BLb + boff[nf][0]];
      bfr[nf][1] = *(const bf16x8*)&lds[BLb + boff[nf][1]];
    }
    PHASE(0, G_STAGE(A,  aRow0, 0, t1, ALn), NOWAIT);
    PHASE(1, G_STAGE(A,  aRow0, 1, t1, ALn), NOWAIT);
    PHASE(2, G_STAGE(Bt, bRow0, 0, t2, BLb), NOWAIT);
    PHASE(3, G_STAGE(Bt, bRow0, 1, t2, BLb), VM4);
  }

  asm volatile("s_waitcnt vmcnt(0)" ::: "memory");
  __builtin_amdgcn_s_barrier();

  int erow = l >> 2, ecc = l & 3;
  if (EPI == 0){
    ushort_t* tw = lds + w*1152;
    #pragma unroll
    for (int mf=0; mf<8; mf++){
      #pragma unroll
      for (int nf=0; nf<4; nf++){
        float bz = bias[n0 + wn*64 + nf*16 + lr];
        #pragma unroll
        for (int rg=0; rg<4; rg++)
          tw[(lk*4+rg)*72 + nf*16 + lr] = f2bf(acc[mf][nf][rg] + bz);
      }
      short8 p0 = *(const short8*)(tw + erow*72 + ecc*16);
      short8 p1 = *(const short8*)(tw + erow*72 + ecc*16 + 8);
      int grow = m0 + wm*128 + mf*16 + erow;
      int col  = n0 + wn*64 + ecc*16;
      *(short8*)&((ushort_t*)Cout_v)[(size_t)grow*N + col]     = p0;
      *(short8*)&((ushort_t*)Cout_v)[(size_t)grow*N + col + 8] = p1;
    }
  } else {
    float* twf = (float*)lds + w*1152;
    #pragma unroll
    for (int mf=0; mf<8; mf++){
      #pragma unroll
      for (int nf=0; nf<4; nf++){
        float bz = bias[n0 + wn*64 + nf*16 + lr];
        #pragma unroll
        for (int rg=0; rg<4; rg++)
          twf[(lk*4+rg)*72 + nf*16 + lr] = acc[mf][nf][rg] + bz;
      }
      int grow = m0 + wm*128 + mf*16 + erow;
      int col  = n0 + wn*64 + ecc*16;
      float4 q0 = *(const float4*)(twf + erow*72 + ecc*16);
      float4 q1 = *(const float4*)(twf + erow*72 + ecc*16 + 4);
      float4 q2 = *(const float4*)(twf + erow*72 + ecc*16 + 8);
      float4 q3 = *(const float4*)(twf + erow*72 + ecc*16 + 12);
      size_t off;
      float* o = (float*)Cout_v;
      if (EPI == 2){
        int row2 = win_map_row(grow);
        off = (size_t)row2*512 + col;
        float4 x0 = *(const float4*)(xres + off);
        float4 x1 = *(const float4*)(xres + off + 4);
        float4 x2 = *(const float4*)(xres + off + 8);
        float4 x3 = *(const float4*)(xres + off + 12);
        q0 = make_float4(q0.x+x0.x, q0.y+x0.y, q0.z+x0.z, q0.w+x0.w);
        q1 = make_float4(q1.x+x1.x, q1.y+x1.y, q1.z+x1.z, q1.w+x1.w);
        q2 = make_float4(q2.x+x2.x, q2.y+x2.y, q2.z+x2.z, q2.w+x2.w);
        q3 = make_float4(q3.x+x3.x, q3.y+x3.y, q3.z+x3.z, q3.w+x3.w);
      } else {
        off = (size_t)grow*N + col;
        float4 x0 = *(const float4*)(o + off);
        float4 x1 = *(const float4*)(o + off + 4);
        float4 x2 = *(const float4*)(o + off + 8);
        float4 x3 = *(const float4*)(o + off + 12);
        q0 = make_float4(q0.x+x0.x, q0.y+x0.y, q0.z+x0.z, q0.w+x0.w);
        q1 = make_float4(q1.x+x1.x, q1.y+x1.y, q1.z+x1.z, q1.w+x1.w);
        q2 = make_float4(q2.x+x2.x, q2.y+x2.y, q2.z+x2.z, q2.w+x2.w);
        q3 = make_float4(q3.x+x3.x, q3.y+x3.y, q3.z+x3.z, q3.w+x3.w);
      }
      *(float4*)(o + off)      = q0;
      *(float4*)(o + off + 4)  = q1;
      *(float4*)(o + off + 8)  = q2;
      *(float4*)(o + off + 12) = q3;
    }
  }
}

// ---------------- FC1 GEMM: 256x128 tile, BK=32, 8 waves, 2-buffer, 2 blk/CU ----------------
// EPI 1: bf16 store after nearest-neighbor 2048-bin double-gelu table.
template<int EPI>
__global__ __launch_bounds__(512, 4) void gemmv(
    const ushort_t* __restrict__ A, const ushort_t* __restrict__ Bt,
    const float* __restrict__ bias, void* __restrict__ Cout_v,
    const float* __restrict__ xres, int M, int N, int K, int nbn)
{
  __shared__ ushort_t lds[24576];                  // 48 KB: buf b at b*12288
  __shared__ float g2tab[(EPI==1)?2048:1];         // 8 KB table (EPI 1 only)
  const int tid = threadIdx.x; const int l = tid & 63; const int w = tid >> 6;
  const int wm = w >> 1, wn = w & 1;
  int m0, n0; remap_mn(blockIdx.x, gridDim.x, nbn, 256, 128, m0, n0);
  const int lr = l & 15, lk = l >> 4;
  const int nt = K >> 5;                           // K-tiles of 32

  if (EPI == 1){
    #pragma unroll
    for (int i=0;i<4;i++){
      int idx = tid*4 + i;
      float vi = -4.f + (float)idx*(1.f/256.f);
      g2tab[idx] = gelu_fast(gelu_fast(vi));
    }
  }

  const int r0 = tid >> 2;
  const int kc = ((tid & 3) - (r0 >> 1)) & 3;
  const size_t aG = (size_t)(m0 + r0) * K + kc*8;
  const size_t bG = (size_t)(n0 + r0) * K + kc*8;

  #define STAGE_T(tt, LB) do { \
    load_lds16(A  + aG +                  (size_t)(tt)*32, &lds[(LB) +        w*512]); \
    load_lds16(A  + aG + 128*(size_t)K +  (size_t)(tt)*32, &lds[(LB) + 4096 + w*512]); \
    load_lds16(Bt + bG +                  (size_t)(tt)*32, &lds[(LB) + 8192 + w*512]); \
  } while(0)

  int aoff[4], boff[4];
  #pragma unroll
  for (int mf=0; mf<4; mf++){
    int row = wm*64 + mf*16 + lr;
    aoff[mf] = (row*4 + ((lk + (row>>1)) & 3))*8;
  }
  #pragma unroll
  for (int nf=0; nf<4; nf++){
    int row = wn*64 + nf*16 + lr;
    boff[nf] = 8192 + (row*4 + ((lk + (row>>1)) & 3))*8;
  }

  f32x4 acc[4][4] = {};

  STAGE_T(0, 0);
  STAGE_T(1, 12288);
  asm volatile("s_waitcnt vmcnt(3)" ::: "memory");   // tile0 landed; tile1 in flight
  __builtin_amdgcn_s_barrier();

  for (int t = 0; t < nt; ++t){
    const int Lb = (t & 1) ? 12288 : 0;
    const int t2 = (t+2 < nt) ? t+2 : nt-1;          // clamped tail (content unused)
    bf16x8 af[4], bfr[4];
    #pragma unroll
    for (int mf=0; mf<4; mf++) af[mf]  = *(const bf16x8*)&lds[Lb + aoff[mf]];
    #pragma unroll
    for (int nf=0; nf<4; nf++) bfr[nf] = *(const bf16x8*)&lds[Lb + boff[nf]];
    __builtin_amdgcn_sched_barrier(0);
    asm volatile("s_waitcnt lgkmcnt(0)" ::: "memory");
    __builtin_amdgcn_s_barrier();                    // all waves done reading this buf
    __builtin_amdgcn_sched_barrier(0);
    STAGE_T(t2, Lb);                                 // overwrite this buf with tile t+2
    __builtin_amdgcn_sched_barrier(0);
    __builtin_amdgcn_s_setprio(1);
    #pragma unroll
    for (int mf=0; mf<4; mf++)
      #pragma unroll
      for (int nf=0; nf<4; nf++)
        acc[mf][nf] = __builtin_amdgcn_mfma_f32_16x16x32_bf16(af[mf], bfr[nf], acc[mf][nf], 0,0,0);
    __builtin_amdgcn_s_setprio(0);
    __builtin_amdgcn_sched_barrier(0);
    asm volatile("s_waitcnt vmcnt(3)" ::: "memory"); // next tile's 3 loads landed
    __builtin_amdgcn_s_barrier();
  }

  asm volatile("s_waitcnt vmcnt(0)" ::: "memory");
  __builtin_amdgcn_s_barrier();
  __builtin_amdgcn_sched_barrier(0);

  int erow = l >> 2, ecc = l & 3;
  ushort_t* tw = lds + w*1152;                     // 16 x stride 72 bf16 = 2304 B/wave
  #pragma unroll
  for (int mf=0; mf<4; mf++){
    #pragma unroll
    for (int nf=0; nf<4; nf++){
      float bz = bias[n0 + wn*64 + nf*16 + lr];
      #pragma unroll
      for (int rg=0; rg<4; rg++){
        float v = acc[mf][nf][rg] + bz;
        if (EPI == 1){
          float u  = fminf(fmaxf(fmaf(v, 256.f, 1024.5f), 0.f), 2047.f);
          float rr = g2tab[(int)u];
          rr = (v >  4.f) ? v   : rr;
          v  = (v < -4.f) ? 0.f : rr;
        }
        tw[(lk*4+rg)*72 + nf*16 + lr] = f2bf(v);
      }
    }
    short8 p0 = *(const short8*)(tw + erow*72 + ecc*16);
    short8 p1 = *(const short8*)(tw + erow*72 + ecc*16 + 8);
    int grow = m0 + wm*64 + mf*16 + erow;
    int col  = n0 + wn*64 + ecc*16;
    *(short8*)&((ushort_t*)Cout_v)[(size_t)grow*N + col]     = p0;
    *(short8*)&((ushort_t*)Cout_v)[(size_t)grow*N + col + 8] = p1;
  }
  #undef STAGE_T
}

// ---------------- FC2 split-K GEMM: 256x128 tile, K-slice=512, atomicAdd f32 out ----------------
// grid = 2048 = 4 kslices x 512 tiles (128 m-blocks x 4 n-blocks). out already
// holds the residual; each slice atomically adds its partial. bias: slice 0 only.
__global__ __launch_bounds__(512, 4) void gemmsk(
    const ushort_t* __restrict__ A, const ushort_t* __restrict__ Bt,
    const float* __restrict__ bias, float* __restrict__ Cout, int M, int N, int K)
{
  __shared__ ushort_t lds[24576];                  // 48 KB -> 3 blocks/CU
  const int tid = threadIdx.x; const int l = tid & 63; const int w = tid >> 6;
  const int wm = w >> 1, wn = w & 1;
  const int nwg = gridDim.x;                       // 2048
  int q    = nwg >> 3;
  int lbid = ((blockIdx.x & 7)*q + (blockIdx.x >> 3));
  const int ksl  = lbid >> 9;                      // 0..3
  const int tile = lbid & 511;                     // 0..511
  const int m0 = (tile >> 2) * 256;                // 128 m-blocks
  const int n0 = (tile & 3) * 128;                 // 4 n-blocks
  const int lr = l & 15, lk = l >> 4;
  const int nt = 16;                               // 512 / 32

  const int r0 = tid >> 2;
  const int kc = ((tid & 3) - (r0 >> 1)) & 3;
  const size_t aG = (size_t)(m0 + r0) * K + (size_t)ksl*512 + kc*8;
  const size_t bG = (size_t)(n0 + r0) * K + (size_t)ksl*512 + kc*8;

  #define STAGE_T(tt, LB) do { \
    load_lds16(A  + aG +                  (size_t)(tt)*32, &lds[(LB) +        w*512]); \
    load_lds16(A  + aG + 128*(size_t)K +  (size_t)(tt)*32, &lds[(LB) + 4096 + w*512]); \
    load_lds16(Bt + bG +                  (size_t)(tt)*32, &lds[(LB) + 8192 + w*512]); \
  } while(0)

  int aoff[4], boff[4];
  #pragma unroll
  for (int mf=0; mf<4; mf++){
    int row = wm*64 + mf*16 + lr;
    aoff[mf] = (row*4 + ((lk + (row>>1)) & 3))*8;
  }
  #pragma unroll
  for (int nf=0; nf<4; nf++){
    int row = wn*64 + nf*16 + lr;
    boff[nf] = 8192 + (row*4 + ((lk + (row>>1)) & 3))*8;
  }

  f32x4 acc[4][4] = {};

  STAGE_T(0, 0);
  STAGE_T(1, 12288);
  asm volatile("s_waitcnt vmcnt(3)" ::: "memory");
  __builtin_amdgcn_s_barrier();

  for (int t = 0; t < nt; ++t){
    const int Lb = (t & 1) ? 12288 : 0;
    const int t2 = (t+2 < nt) ? t+2 : nt-1;
    bf16x8 af[4], bfr[4];
    #pragma unroll
    for (int mf=0; mf<4; mf++) af[mf]  = *(const bf16x8*)&lds[Lb + aoff[mf]];
    #pragma unroll
    for (int nf=0; nf<4; nf++) bfr[nf] = *(const bf16x8*)&lds[Lb + boff[nf]];
    __builtin_amdgcn_sched_barrier(0);
    asm volatile("s_waitcnt lgkmcnt(0)" ::: "memory");
    __builtin_amdgcn_s_barrier();
    __builtin_amdgcn_sched_barrier(0);
    STAGE_T(t2, Lb);
    __builtin_amdgcn_sched_barrier(0);
    __builtin_amdgcn_s_setprio(1);
    #pragma unroll
    for (int mf=0; mf<4; mf++)
      #pragma unroll
      for (int nf=0; nf<4; nf++)
        acc[mf][nf] = __builtin_amdgcn_mfma_f32_16x16x32_bf16(af[mf], bfr[nf], acc[mf][nf], 0,0,0);
    __builtin_amdgcn_s_setprio(0);
    __builtin_amdgcn_sched_barrier(0);
    asm volatile("s_waitcnt vmcnt(3)" ::: "memory");
    __builtin_amdgcn_s_barrier();
  }

  // epilogue: direct scalar atomicAdd (C/D layout col=lane&15, row=(lane>>4)*4+reg)
  #pragma unroll
  for (int mf=0; mf<4; mf++){
    int rbase = m0 + wm*64 + mf*16 + lk*4;
    #pragma unroll
    for (int nf=0; nf<4; nf++){
      int col = n0 + wn*64 + nf*16 + lr;
      float bz = (ksl == 0) ? bias[col] : 0.f;
      #pragma unroll
      for (int rg=0; rg<4; rg++){
        atomicAdd(&Cout[(size_t)(rbase+rg)*N + col], acc[mf][nf][rg] + bz);
      }
    }
  }
  #undef STAGE_T
}

// ---------------- windowed attention: one wave per (window, head) ----------------
DEVINL int band3(int t){ return (t<56) ? 0 : ((t<60) ? 1 : 2); }

__global__ __launch_bounds__(256) void attn_kernel(const ushort_t* __restrict__ qkv,
    const float* __restrict__ rpb, ushort_t* __restrict__ o)
{
  __shared__ ushort_t sP[4][64*64];
  __shared__ ushort_t sV[4][64*32];
  int tid = threadIdx.x; int l = tid & 63; int w = tid >> 6;
  int p = blockIdx.x*4 + w;
  int bw = p >> 4, head = p & 15;
  int lr = l & 15, lk = l >> 4;
  const ushort_t* base = qkv + (size_t)bw*64*1536 + head*32;

  #pragma unroll
  for (int c=0;c<4;c++){
    int idx = c*64 + l;
    int row = idx >> 2, cc = idx & 3;
    load_lds16(base + 1024 + (size_t)row*1536 + cc*8, &sV[w][0] + c*512);
  }

  bf16x8 qf[4], kf[4];
  #pragma unroll
  for (int m=0;m<4;m++) qf[m] = *(const bf16x8*)(base +       (size_t)(m*16+lr)*1536 + lk*8);
  #pragma unroll
  for (int m=0;m<4;m++) kf[m] = *(const bf16x8*)(base + 512 + (size_t)(m*16+lr)*1536 + lk*8);

  f32x4 s[4][4] = {};
  #pragma unroll
  for (int m=0;m<4;m++)
    #pragma unroll
    for (int n=0;n<4;n++)
      s[m][n] = __builtin_amdgcn_mfma_f32_16x16x32_bf16(qf[m], kf[n], s[m][n], 0,0,0);

  int wdx = bw & 63; int wh = wdx >> 3, ww = wdx & 7;
  const float SCALE = 0.17677669529663687f;
  #pragma unroll
  for (int m=0;m<4;m++){
    #pragma unroll
    for (int r=0;r<4;r++){
      int i  = m*16 + lk*4 + r;
      int ri = band3(wh*8 + (i>>3))*3 + band3(ww*8 + (i&7));
      int ix = i & 7, iy = i >> 3;
      #pragma unroll
      for (int n=0;n<4;n++){
        int j   = n*16 + lr;
        int rj  = band3(wh*8 + (j>>3))*3 + band3(ww*8 + (j&7));
        int idx = 15*(ix - (j&7) + 7) + (iy - (j>>3) + 7);
        float bv = rpb[idx*16 + head];
        float mk = (ri == rj) ? 0.f : -100.f;
        s[m][n][r] = s[m][n][r]*SCALE + bv + mk;
      }
    }
  }

  #pragma unroll
  for (int pass=0; pass<2; pass++){
    #pragma unroll
    for (int m=0;m<4;m++){
      #pragma unroll
      for (int r=0;r<4;r++){
        float mx = fmaxf(fmaxf(s[m][0][r], s[m][1][r]), fmaxf(s[m][2][r], s[m][3][r]));
        #pragma unroll
        for (int d=1;d<16;d<<=1) mx = fmaxf(mx, __shfl_xor(mx, d));
        float sum = 0.f;
        #pragma unroll
        for (int n=0;n<4;n++){ float e = __expf(s[m][n][r]-mx); s[m][n][r]=e; sum += e; }
        #pragma unroll
        for (int d=1;d<16;d<<=1) sum += __shfl_xor(sum, d);
        float inv = 1.f/sum;
        #pragma unroll
        for (int n=0;n<4;n++) s[m][n][r] = s[m][n][r]*inv;
      }
    }
  }

  ushort_t* pl = &sP[w][0];
  #pragma unroll
  for (int m=0;m<4;m++)
    #pragma unroll
    for (int r=0;r<4;r++){
      int i = m*16 + lk*4 + r;
      #pragma unroll
      for (int n=0;n<4;n++){
        int j = n*16 + lr;
        int byte = i*128 + ((j*2) ^ ((i&7)<<4));
        pl[byte>>1] = f2bf(s[m][n][r]);
      }
    }

  asm volatile("s_waitcnt vmcnt(0)" ::: "memory");
  const ushort_t* vl = &sV[w][0];
  frag_u vf[2][2];
  #pragma unroll
  for (int kb=0;kb<2;kb++)
    #pragma unroll
    for (int nb=0;nb<2;nb++){
      #pragma unroll
      for (int j=0;j<8;j++){
        int k = kb*32 + lk*8 + j;
        vf[kb][nb].s[j] = (short)vl[k*32 + nb*16 + lr];
      }
    }

  f32x4 oacc[4][2] = {};
  #pragma unroll
  for (int m=0;m<4;m++){
    #pragma unroll
    for (int kb=0;kb<2;kb++){
      int row  = m*16 + lr;
      int byte = row*128 + ((kb*64 + lk*16) ^ ((row&7)<<4));
      bf16x8 pf = *(const bf16x8*)(pl + (byte>>1));
      #pragma unroll
      for (int nb=0;nb<2;nb++)
        oacc[m][nb] = __builtin_amdgcn_mfma_f32_16x16x32_bf16(pf, vf[kb][nb].b, oacc[m][nb], 0,0,0);
    }
  }

  ushort_t* orow = o + (size_t)bw*64*512 + head*32;
  #pragma unroll
  for (int m=0;m<4;m++)
    #pragma unroll
    for (int nb=0;nb<2;nb++)
      #pragma unroll
      for (int r=0;r<4;r++){
        int i = m*16 + lk*4 + r;
        int d = nb*16 + lr;
        orow[(size_t)i*512 + d] = f2bf(oacc[m][nb][r]);
      }
}

// ---------------- launch ----------------
extern "C" void kernel_launch(void* const* d_in, const int* in_sizes, int n_in,
                              void* d_out, int out_size, void* d_ws, size_t ws_size,
                              hipStream_t stream) {
  const float* x      = (const float*)d_in[0];
  const float* n1g    = (const float*)d_in[1];
  const float* n1b    = (const float*)d_in[2];
  const float* qkv_w  = (const float*)d_in[3];
  const float* qkv_b  = (const float*)d_in[4];
  const float* rpb    = (const float*)d_in[5];
  const float* proj_w = (const float*)d_in[6];
  const float* proj_b = (const float*)d_in[7];
  const float* n2g    = (const float*)d_in[8];
  const float* n2b    = (const float*)d_in[9];
  const float* fc1_w  = (const float*)d_in[10];
  const float* fc1_b  = (const float*)d_in[11];
  const float* fc2_w  = (const float*)d_in[12];
  const float* fc2_b  = (const float*)d_in[13];
  float* out = (float*)d_out;

  ushort_t* ws = (ushort_t*)d_ws;
  size_t off = 0;
  ushort_t* wqT = ws + off; off += (size_t)1536*512;
  ushort_t* wpT = ws + off; off += (size_t)512*512;
  ushort_t* w1T = ws + off; off += (size_t)2048*512;
  ushort_t* w2T = ws + off; off += (size_t)512*2048;
  ushort_t* R1  = ws + off; off += (size_t)32768*512;   // hwin -> owin -> ln2out
  ushort_t* R2  = ws + off; off += (size_t)32768*2048;  // qkv -> fc1out
  if (ws_size < off*sizeof(ushort_t)) return;           // workspace too small: fail cleanly

  transpose_all<<<3072, dim3(32,8), 0, stream>>>(qkv_w, proj_w, fc1_w, fc2_w, wqT, wpT, w1T, w2T);

  ln_kernel<<<8192, 256, 0, stream>>>(x, n1g, n1b, R1, 1);
  gemm256<0><<<768, 512, 0, stream>>>(R1, wqT, qkv_b, R2, nullptr, 32768, 1536, 512, 6);
  attn_kernel<<<2048, 256, 0, stream>>>(R2, rpb, R1);
  gemm256<2><<<256, 512, 0, stream>>>(R1, wpT, proj_b, out, x, 32768, 512, 512, 2);
  ln_kernel<<<8192, 256, 0, stream>>>(out, n2g, n2b, R1, 0);
  gemmv<1><<<2048, 512, 0, stream>>>(R1, w1T, fc1_b, R2, nullptr, 32768, 2048, 512, 16);
  gemmsk<<<2048, 512, 0, stream>>>(R2, w2T, fc2_b, out, 32768, 512, 2048);
}

// Round 14
// 383.104 us; speedup vs baseline: 1.3996x; 1.3996x over previous
//
#include <hip/hip_runtime.h>
#include <hip/hip_bf16.h>
#include <math.h>

// Swin block, MI355X. f32 inputs -> f32 output. B=8, H=W=64, C=512, HEADS=16,
// WS=8, SHIFT=4, N=64 tok/window, NW=64, HEAD_DIM=32, HIDDEN=2048, M=32768.
// Round 14: revert to the verified-best r10 config (389.5 us): QKV/proj/FC2 on
// gemm256 (256x256 8-phase counted-vmcnt), FC1 on gemmv (256x128 2-buf) with
// 2048-bin NN double-gelu table. Split-K (r13: atomics 2.2x worse) abandoned.

typedef unsigned short ushort_t;
typedef __attribute__((ext_vector_type(8))) short short8;
typedef __attribute__((ext_vector_type(8))) __bf16 bf16x8;
typedef __attribute__((ext_vector_type(4))) float f32x4;

#define DEVINL __device__ __forceinline__

union frag_u { short8 s; bf16x8 b; };

DEVINL float bf2f(ushort_t u){ union {unsigned int i; float f;} c; c.i = ((unsigned)u)<<16; return c.f; }
DEVINL ushort_t f2bf(float f){ union {unsigned int i; float f;} c; c.f = f; unsigned r = c.i + 0x7fffu + ((c.i>>16)&1u); return (ushort_t)(r>>16); }

typedef const __attribute__((address_space(1))) void* gas_t;
typedef __attribute__((address_space(3))) void* las_t;
DEVINL void load_lds16(const void* g, void* l) {
  __builtin_amdgcn_global_load_lds((gas_t)g, (las_t)l, 16, 0, 0);
}

// exact-GELU via Abramowitz-Stegun 7.1.25 erf (|err| <= 2.5e-5; bf16-invisible)
DEVINL float gelu_fast(float v){
  float z  = fabsf(v) * 0.70710678118654752f;
  float t  = __builtin_amdgcn_rcpf(fmaf(0.47047f, z, 1.0f));
  float p  = t * fmaf(t, fmaf(t, 0.7478556f, -0.0958798f), 0.3480242f);
  float e  = __expf(-z*z);
  float er = fmaf(-p, e, 1.0f);                 // erf(z), z>=0
  float hs = (v >= 0.f) ? 0.5f : -0.5f;
  return v * fmaf(hs, er, 0.5f);
}

// window-order token t -> source/dest row in [B, H*W] (includes the ±SHIFT roll)
DEVINL int win_map_row(int t){
  int bw = t >> 6, n = t & 63;
  int b  = bw >> 6, wdx = bw & 63;
  int wh = wdx >> 3, ww = wdx & 7;
  int r  = n >> 3,  c  = n & 7;
  int hh = (wh*8 + r + 4) & 63;
  int w2 = (ww*8 + c + 4) & 63;
  return (b << 12) + (hh << 6) + w2;
}

// XCD-chunked bijective block remap (nwg % 8 == 0), n-fastest logical order
DEVINL void remap_mn(int bid, int nwg, int nbn, int BM, int BN, int& m0, int& n0){
  int q    = nwg >> 3;
  int lbid = (bid & 7)*q + (bid >> 3);
  m0 = (lbid / nbn) * BM;
  n0 = (lbid % nbn) * BN;
}

// ---------------- merged transpose: 4 weights f32 -> bf16 B^T layout ----------------
__global__ void transpose_all(const float* __restrict__ qkv_w, const float* __restrict__ proj_w,
                              const float* __restrict__ fc1_w, const float* __restrict__ fc2_w,
                              ushort_t* __restrict__ wqT, ushort_t* __restrict__ wpT,
                              ushort_t* __restrict__ w1T, ushort_t* __restrict__ w2T){
  __shared__ float t[32][33];
  int bid = blockIdx.x;
  const float* in; ushort_t* out; int R, Ccols, bx, by;
  if (bid < 768)      { in=qkv_w;  out=wqT; R=512;  Ccols=1536; bx=(bid%48)*32;        by=(bid/48)*32; }
  else if (bid < 1024){ int b=bid-768;  in=proj_w; out=wpT; R=512;  Ccols=512;  bx=(b%16)*32; by=(b/16)*32; }
  else if (bid < 2048){ int b=bid-1024; in=fc1_w;  out=w1T; R=512;  Ccols=2048; bx=(b%64)*32; by=(b/64)*32; }
  else                { int b=bid-2048; in=fc2_w;  out=w2T; R=2048; Ccols=512;  bx=(b%16)*32; by=(b/16)*32; }
  int x = threadIdx.x, y = threadIdx.y;
  #pragma unroll
  for (int i=0;i<32;i+=8) t[y+i][x] = in[(size_t)(by+y+i)*Ccols + bx + x];
  __syncthreads();
  #pragma unroll
  for (int i=0;i<32;i+=8) out[(size_t)(bx+y+i)*R + by + x] = f2bf(t[x][y+i]);
}

// ---------------- LayerNorm f32-in, bf16-out (optional shift+window gather) ----------------
__global__ __launch_bounds__(256) void ln_kernel(const float* __restrict__ in,
    const float* __restrict__ g, const float* __restrict__ bta,
    ushort_t* __restrict__ out, int windowed){
  int tid = threadIdx.x; int l = tid & 63; int w = tid >> 6;
  int t = blockIdx.x * 4 + w;
  int src = windowed ? win_map_row(t) : t;
  const float* row = in + (size_t)src * 512;
  float4 v0 = *(const float4*)(row + l*8);
  float4 v1 = *(const float4*)(row + l*8 + 4);
  float f[8] = {v0.x,v0.y,v0.z,v0.w, v1.x,v1.y,v1.z,v1.w};
  float s=0.f, s2=0.f;
  #pragma unroll
  for (int j=0;j<8;j++){ s += f[j]; s2 += f[j]*f[j]; }
  #pragma unroll
  for (int m=1;m<64;m<<=1){ s += __shfl_xor(s,m); s2 += __shfl_xor(s2,m); }
  float mu  = s * (1.f/512.f);
  float var = s2*(1.f/512.f) - mu*mu;
  float rs  = rsqrtf(var + 1e-3f);
  float4 g0 = *(const float4*)(g + l*8),   g1 = *(const float4*)(g + l*8 + 4);
  float4 b0 = *(const float4*)(bta + l*8), b1 = *(const float4*)(bta + l*8 + 4);
  float gg[8] = {g0.x,g0.y,g0.z,g0.w, g1.x,g1.y,g1.z,g1.w};
  float bb[8] = {b0.x,b0.y,b0.z,b0.w, b1.x,b1.y,b1.z,b1.w};
  short8 o;
  #pragma unroll
  for (int j=0;j<8;j++) o[j] = (short)f2bf((f[j]-mu)*rs*gg[j] + bb[j]);
  *(short8*)(out + (size_t)t*512 + l*8) = o;
}

// ---------------- GEMM 256x256, BK=64, 8 waves, 8-phase counted-vmcnt ----------------
// EPI 0: bf16 short8 store; 2: f32 float4 scatter out[win_map_row] = xres + v;
// EPI 3: f32 float4 out += v.  All via per-wave LDS transpose.
#define G_STAGE(G, base, h, tt, LB) do { \
    load_lds16((G) + (base) + (size_t)((h)*128)*K    + (size_t)(tt)*64, &lds[(LB) + (h)*8192 +        w*512]); \
    load_lds16((G) + (base) + (size_t)((h)*128+64)*K + (size_t)(tt)*64, &lds[(LB) + (h)*8192 + 4096 + w*512]); \
  } while(0)

#define NOWAIT
#define VM4 asm volatile("s_waitcnt vmcnt(4)" ::: "memory")

#define PHASE(mp, STAGE_STMT, EXTRA) do { \
    bf16x8 a0 = *(const bf16x8*)&lds[ALb + aoff[2*(mp)  ][0]]; \
    bf16x8 a1 = *(const bf16x8*)&lds[ALb + aoff[2*(mp)  ][1]]; \
    bf16x8 a2 = *(const bf16x8*)&lds[ALb + aoff[2*(mp)+1][0]]; \
    bf16x8 a3 = *(const bf16x8*)&lds[ALb + aoff[2*(mp)+1][1]]; \
    STAGE_STMT; \
    EXTRA; \
    __builtin_amdgcn_s_barrier(); \
    asm volatile("s_waitcnt lgkmcnt(0)" ::: "memory"); \
    __builtin_amdgcn_sched_barrier(0); \
    __builtin_amdgcn_s_setprio(1); \
    _Pragma("unroll") \
    for (int nf=0; nf<4; nf++){ \
      acc[2*(mp)  ][nf] = __builtin_amdgcn_mfma_f32_16x16x32_bf16(a0, bfr[nf][0], acc[2*(mp)  ][nf], 0,0,0); \
      acc[2*(mp)  ][nf] = __builtin_amdgcn_mfma_f32_16x16x32_bf16(a1, bfr[nf][1], acc[2*(mp)  ][nf], 0,0,0); \
      acc[2*(mp)+1][nf] = __builtin_amdgcn_mfma_f32_16x16x32_bf16(a2, bfr[nf][0], acc[2*(mp)+1][nf], 0,0,0); \
      acc[2*(mp)+1][nf] = __builtin_amdgcn_mfma_f32_16x16x32_bf16(a3, bfr[nf][1], acc[2*(mp)+1][nf], 0,0,0); \
    } \
    __builtin_amdgcn_s_setprio(0); \
    __builtin_amdgcn_sched_barrier(0); \
    __builtin_amdgcn_s_barrier(); \
  } while(0)

template<int EPI>
__global__ __launch_bounds__(512, 2) void gemm256(
    const ushort_t* __restrict__ A, const ushort_t* __restrict__ Bt,
    const float* __restrict__ bias, void* __restrict__ Cout_v,
    const float* __restrict__ xres, int M, int N, int K, int nbn)
{
  __shared__ ushort_t lds[65536];   // 128 KiB: 2 bufs x (A 32KB + B 32KB)
  const int tid = threadIdx.x; const int l = tid & 63; const int w = tid >> 6;
  const int wm = w >> 2, wn = w & 3;
  int m0, n0;
  remap_mn(blockIdx.x, gridDim.x, nbn, 256, 256, m0, n0);
  const int lr = l & 15, lk = l >> 4;
  const int nt = K >> 6;                 // K-tiles of 64

  const int r0 = tid >> 3;
  const int kc = ((tid & 7) - r0) & 7;
  const size_t aRow0 = (size_t)(m0 + r0) * K + kc * 8;
  const size_t bRow0 = (size_t)(n0 + r0) * K + kc * 8;

  int aoff[8][2], boff[4][2];
  #pragma unroll
  for (int mf=0; mf<8; mf++){
    int row = wm*128 + mf*16 + lr;
    #pragma unroll
    for (int kh=0; kh<2; kh++){ int c = kh*4 + lk; aoff[mf][kh] = (row*8 + ((c + row)&7))*8; }
  }
  #pragma unroll
  for (int nf=0; nf<4; nf++){
    int row = wn*64 + nf*16 + lr;
    #pragma unroll
    for (int kh=0; kh<2; kh++){ int c = kh*4 + lk; boff[nf][kh] = (row*8 + ((c + row)&7))*8; }
  }

  f32x4 acc[8][4] = {};

  G_STAGE(A,  aRow0, 0, 0, 0);
  G_STAGE(A,  aRow0, 1, 0, 0);
  G_STAGE(Bt, bRow0, 0, 0, 16384);
  G_STAGE(Bt, bRow0, 1, 0, 16384);
  G_STAGE(Bt, bRow0, 0, 1, 32768+16384);
  G_STAGE(Bt, bRow0, 1, 1, 32768+16384);
  VM4;
  __builtin_amdgcn_s_barrier();

  for (int t = 0; t < nt; ++t) {
    const int b   = t & 1;
    const int ALb = b*32768, BLb = ALb + 16384;
    const int ALn = (b^1)*32768;
    const int t1  = (t+1 < nt) ? t+1 : t;
    const int t2  = (t+2 < nt) ? t+2 : t;

    bf16x8 bfr[4][2];
    #pragma unroll
    for (int nf=0; nf<4; nf++){
      bfr[nf][0] = *(const bf16x8*)&lds[BLb + boff[nf][0]];
      bfr[nf][1] = *(const bf16x8*)&lds[BLb + boff[nf][1]];
    }
    PHASE(0, G_STAGE(A,  aRow0, 0, t1, ALn), NOWAIT);
    PHASE(1, G_STAGE(A,  aRow0, 1, t1, ALn), NOWAIT);
    PHASE(2, G_STAGE(Bt, bRow0, 0, t2, BLb), NOWAIT);
    PHASE(3, G_STAGE(Bt, bRow0, 1, t2, BLb), VM4);
  }

  asm volatile("s_waitcnt vmcnt(0)" ::: "memory");
  __builtin_amdgcn_s_barrier();

  int erow = l >> 2, ecc = l & 3;
  if (EPI == 0){
    ushort_t* tw = lds + w*1152;
    #pragma unroll
    for (int mf=0; mf<8; mf++){
      #pragma unroll
      for (int nf=0; nf<4; nf++){
        float bz = bias[n0 + wn*64 + nf*16 + lr];
        #pragma unroll
        for (int rg=0; rg<4; rg++)
          tw[(lk*4+rg)*72 + nf*16 + lr] = f2bf(acc[mf][nf][rg] + bz);
      }
      short8 p0 = *(const short8*)(tw + erow*72 + ecc*16);
      short8 p1 = *(const short8*)(tw + erow*72 + ecc*16 + 8);
      int grow = m0 + wm*128 + mf*16 + erow;
      int col  = n0 + wn*64 + ecc*16;
      *(short8*)&((ushort_t*)Cout_v)[(size_t)grow*N + col]     = p0;
      *(short8*)&((ushort_t*)Cout_v)[(size_t)grow*N + col + 8] = p1;
    }
  } else {
    float* twf = (float*)lds + w*1152;
    #pragma unroll
    for (int mf=0; mf<8; mf++){
      #pragma unroll
      for (int nf=0; nf<4; nf++){
        float bz = bias[n0 + wn*64 + nf*16 + lr];
        #pragma unroll
        for (int rg=0; rg<4; rg++)
          twf[(lk*4+rg)*72 + nf*16 + lr] = acc[mf][nf][rg] + bz;
      }
      int grow = m0 + wm*128 + mf*16 + erow;
      int col  = n0 + wn*64 + ecc*16;
      float4 q0 = *(const float4*)(twf + erow*72 + ecc*16);
      float4 q1 = *(const float4*)(twf + erow*72 + ecc*16 + 4);
      float4 q2 = *(const float4*)(twf + erow*72 + ecc*16 + 8);
      float4 q3 = *(const float4*)(twf + erow*72 + ecc*16 + 12);
      size_t off;
      float* o = (float*)Cout_v;
      if (EPI == 2){
        int row2 = win_map_row(grow);
        off = (size_t)row2*512 + col;
        float4 x0 = *(const float4*)(xres + off);
        float4 x1 = *(const float4*)(xres + off + 4);
        float4 x2 = *(const float4*)(xres + off + 8);
        float4 x3 = *(const float4*)(xres + off + 12);
        q0 = make_float4(q0.x+x0.x, q0.y+x0.y, q0.z+x0.z, q0.w+x0.w);
        q1 = make_float4(q1.x+x1.x, q1.y+x1.y, q1.z+x1.z, q1.w+x1.w);
        q2 = make_float4(q2.x+x2.x, q2.y+x2.y, q2.z+x2.z, q2.w+x2.w);
        q3 = make_float4(q3.x+x3.x, q3.y+x3.y, q3.z+x3.z, q3.w+x3.w);
      } else {
        off = (size_t)grow*N + col;
        float4 x0 = *(const float4*)(o + off);
        float4 x1 = *(const float4*)(o + off + 4);
        float4 x2 = *(const float4*)(o + off + 8);
        float4 x3 = *(const float4*)(o + off + 12);
        q0 = make_float4(q0.x+x0.x, q0.y+x0.y, q0.z+x0.z, q0.w+x0.w);
        q1 = make_float4(q1.x+x1.x, q1.y+x1.y, q1.z+x1.z, q1.w+x1.w);
        q2 = make_float4(q2.x+x2.x, q2.y+x2.y, q2.z+x2.z, q2.w+x2.w);
        q3 = make_float4(q3.x+x3.x, q3.y+x3.y, q3.z+x3.z, q3.w+x3.w);
      }
      *(float4*)(o + off)      = q0;
      *(float4*)(o + off + 4)  = q1;
      *(float4*)(o + off + 8)  = q2;
      *(float4*)(o + off + 12) = q3;
    }
  }
}

// ---------------- FC1 GEMM: 256x128 tile, BK=32, 8 waves, 2-buffer, 2 blk/CU ----------------
// EPI 1: bf16 store after nearest-neighbor 2048-bin double-gelu table.
template<int EPI>
__global__ __launch_bounds__(512, 4) void gemmv(
    const ushort_t* __restrict__ A, const ushort_t* __restrict__ Bt,
    const float* __restrict__ bias, void* __restrict__ Cout_v,
    const float* __restrict__ xres, int M, int N, int K, int nbn)
{
  __shared__ ushort_t lds[24576];                  // 48 KB: buf b at b*12288
  __shared__ float g2tab[(EPI==1)?2048:1];         // 8 KB table (EPI 1 only)
  const int tid = threadIdx.x; const int l = tid & 63; const int w = tid >> 6;
  const int wm = w >> 1, wn = w & 1;
  int m0, n0; remap_mn(blockIdx.x, gridDim.x, nbn, 256, 128, m0, n0);
  const int lr = l & 15, lk = l >> 4;
  const int nt = K >> 5;                           // K-tiles of 32

  if (EPI == 1){
    #pragma unroll
    for (int i=0;i<4;i++){
      int idx = tid*4 + i;
      float vi = -4.f + (float)idx*(1.f/256.f);
      g2tab[idx] = gelu_fast(gelu_fast(vi));
    }
  }

  const int r0 = tid >> 2;
  const int kc = ((tid & 3) - (r0 >> 1)) & 3;
  const size_t aG = (size_t)(m0 + r0) * K + kc*8;
  const size_t bG = (size_t)(n0 + r0) * K + kc*8;

  #define STAGE_T(tt, LB) do { \
    load_lds16(A  + aG +                  (size_t)(tt)*32, &lds[(LB) +        w*512]); \
    load_lds16(A  + aG + 128*(size_t)K +  (size_t)(tt)*32, &lds[(LB) + 4096 + w*512]); \
    load_lds16(Bt + bG +                  (size_t)(tt)*32, &lds[(LB) + 8192 + w*512]); \
  } while(0)

  int aoff[4], boff[4];
  #pragma unroll
  for (int mf=0; mf<4; mf++){
    int row = wm*64 + mf*16 + lr;
    aoff[mf] = (row*4 + ((lk + (row>>1)) & 3))*8;
  }
  #pragma unroll
  for (int nf=0; nf<4; nf++){
    int row = wn*64 + nf*16 + lr;
    boff[nf] = 8192 + (row*4 + ((lk + (row>>1)) & 3))*8;
  }

  f32x4 acc[4][4] = {};

  STAGE_T(0, 0);
  STAGE_T(1, 12288);
  asm volatile("s_waitcnt vmcnt(3)" ::: "memory");   // tile0 landed; tile1 in flight
  __builtin_amdgcn_s_barrier();

  for (int t = 0; t < nt; ++t){
    const int Lb = (t & 1) ? 12288 : 0;
    const int t2 = (t+2 < nt) ? t+2 : nt-1;          // clamped tail (content unused)
    bf16x8 af[4], bfr[4];
    #pragma unroll
    for (int mf=0; mf<4; mf++) af[mf]  = *(const bf16x8*)&lds[Lb + aoff[mf]];
    #pragma unroll
    for (int nf=0; nf<4; nf++) bfr[nf] = *(const bf16x8*)&lds[Lb + boff[nf]];
    __builtin_amdgcn_sched_barrier(0);
    asm volatile("s_waitcnt lgkmcnt(0)" ::: "memory");
    __builtin_amdgcn_s_barrier();                    // all waves done reading this buf
    __builtin_amdgcn_sched_barrier(0);
    STAGE_T(t2, Lb);                                 // overwrite this buf with tile t+2
    __builtin_amdgcn_sched_barrier(0);
    __builtin_amdgcn_s_setprio(1);
    #pragma unroll
    for (int mf=0; mf<4; mf++)
      #pragma unroll
      for (int nf=0; nf<4; nf++)
        acc[mf][nf] = __builtin_amdgcn_mfma_f32_16x16x32_bf16(af[mf], bfr[nf], acc[mf][nf], 0,0,0);
    __builtin_amdgcn_s_setprio(0);
    __builtin_amdgcn_sched_barrier(0);
    asm volatile("s_waitcnt vmcnt(3)" ::: "memory"); // next tile's 3 loads landed
    __builtin_amdgcn_s_barrier();
  }

  asm volatile("s_waitcnt vmcnt(0)" ::: "memory");
  __builtin_amdgcn_s_barrier();
  __builtin_amdgcn_sched_barrier(0);

  int erow = l >> 2, ecc = l & 3;
  ushort_t* tw = lds + w*1152;                     // 16 x stride 72 bf16 = 2304 B/wave
  #pragma unroll
  for (int mf=0; mf<4; mf++){
    #pragma unroll
    for (int nf=0; nf<4; nf++){
      float bz = bias[n0 + wn*64 + nf*16 + lr];
      #pragma unroll
      for (int rg=0; rg<4; rg++){
        float v = acc[mf][nf][rg] + bz;
        if (EPI == 1){
          float u  = fminf(fmaxf(fmaf(v, 256.f, 1024.5f), 0.f), 2047.f);
          float rr = g2tab[(int)u];
          rr = (v >  4.f) ? v   : rr;
          v  = (v < -4.f) ? 0.f : rr;
        }
        tw[(lk*4+rg)*72 + nf*16 + lr] = f2bf(v);
      }
    }
    short8 p0 = *(const short8*)(tw + erow*72 + ecc*16);
    short8 p1 = *(const short8*)(tw + erow*72 + ecc*16 + 8);
    int grow = m0 + wm*64 + mf*16 + erow;
    int col  = n0 + wn*64 + ecc*16;
    *(short8*)&((ushort_t*)Cout_v)[(size_t)grow*N + col]     = p0;
    *(short8*)&((ushort_t*)Cout_v)[(size_t)grow*N + col + 8] = p1;
  }
  #undef STAGE_T
}

// ---------------- windowed attention: one wave per (window, head) ----------------
DEVINL int band3(int t){ return (t<56) ? 0 : ((t<60) ? 1 : 2); }

__global__ __launch_bounds__(256) void attn_kernel(const ushort_t* __restrict__ qkv,
    const float* __restrict__ rpb, ushort_t* __restrict__ o)
{
  __shared__ ushort_t sP[4][64*64];
  __shared__ ushort_t sV[4][64*32];
  int tid = threadIdx.x; int l = tid & 63; int w = tid >> 6;
  int p = blockIdx.x*4 + w;
  int bw = p >> 4, head = p & 15;
  int lr = l & 15, lk = l >> 4;
  const ushort_t* base = qkv + (size_t)bw*64*1536 + head*32;

  #pragma unroll
  for (int c=0;c<4;c++){
    int idx = c*64 + l;
    int row = idx >> 2, cc = idx & 3;
    load_lds16(base + 1024 + (size_t)row*1536 + cc*8, &sV[w][0] + c*512);
  }

  bf16x8 qf[4], kf[4];
  #pragma unroll
  for (int m=0;m<4;m++) qf[m] = *(const bf16x8*)(base +       (size_t)(m*16+lr)*1536 + lk*8);
  #pragma unroll
  for (int m=0;m<4;m++) kf[m] = *(const bf16x8*)(base + 512 + (size_t)(m*16+lr)*1536 + lk*8);

  f32x4 s[4][4] = {};
  #pragma unroll
  for (int m=0;m<4;m++)
    #pragma unroll
    for (int n=0;n<4;n++)
      s[m][n] = __builtin_amdgcn_mfma_f32_16x16x32_bf16(qf[m], kf[n], s[m][n], 0,0,0);

  int wdx = bw & 63; int wh = wdx >> 3, ww = wdx & 7;
  const float SCALE = 0.17677669529663687f;
  #pragma unroll
  for (int m=0;m<4;m++){
    #pragma unroll
    for (int r=0;r<4;r++){
      int i  = m*16 + lk*4 + r;
      int ri = band3(wh*8 + (i>>3))*3 + band3(ww*8 + (i&7));
      int ix = i & 7, iy = i >> 3;
      #pragma unroll
      for (int n=0;n<4;n++){
        int j   = n*16 + lr;
        int rj  = band3(wh*8 + (j>>3))*3 + band3(ww*8 + (j&7));
        int idx = 15*(ix - (j&7) + 7) + (iy - (j>>3) + 7);
        float bv = rpb[idx*16 + head];
        float mk = (ri == rj) ? 0.f : -100.f;
        s[m][n][r] = s[m][n][r]*SCALE + bv + mk;
      }
    }
  }

  #pragma unroll
  for (int pass=0; pass<2; pass++){
    #pragma unroll
    for (int m=0;m<4;m++){
      #pragma unroll
      for (int r=0;r<4;r++){
        float mx = fmaxf(fmaxf(s[m][0][r], s[m][1][r]), fmaxf(s[m][2][r], s[m][3][r]));
        #pragma unroll
        for (int d=1;d<16;d<<=1) mx = fmaxf(mx, __shfl_xor(mx, d));
        float sum = 0.f;
        #pragma unroll
        for (int n=0;n<4;n++){ float e = __expf(s[m][n][r]-mx); s[m][n][r]=e; sum += e; }
        #pragma unroll
        for (int d=1;d<16;d<<=1) sum += __shfl_xor(sum, d);
        float inv = 1.f/sum;
        #pragma unroll
        for (int n=0;n<4;n++) s[m][n][r] = s[m][n][r]*inv;
      }
    }
  }

  ushort_t* pl = &sP[w][0];
  #pragma unroll
  for (int m=0;m<4;m++)
    #pragma unroll
    for (int r=0;r<4;r++){
      int i = m*16 + lk*4 + r;
      #pragma unroll
      for (int n=0;n<4;n++){
        int j = n*16 + lr;
        int byte = i*128 + ((j*2) ^ ((i&7)<<4));
        pl[byte>>1] = f2bf(s[m][n][r]);
      }
    }

  asm volatile("s_waitcnt vmcnt(0)" ::: "memory");
  const ushort_t* vl = &sV[w][0];
  frag_u vf[2][2];
  #pragma unroll
  for (int kb=0;kb<2;kb++)
    #pragma unroll
    for (int nb=0;nb<2;nb++){
      #pragma unroll
      for (int j=0;j<8;j++){
        int k = kb*32 + lk*8 + j;
        vf[kb][nb].s[j] = (short)vl[k*32 + nb*16 + lr];
      }
    }

  f32x4 oacc[4][2] = {};
  #pragma unroll
  for (int m=0;m<4;m++){
    #pragma unroll
    for (int kb=0;kb<2;kb++){
      int row  = m*16 + lr;
      int byte = row*128 + ((kb*64 + lk*16) ^ ((row&7)<<4));
      bf16x8 pf = *(const bf16x8*)(pl + (byte>>1));
      #pragma unroll
      for (int nb=0;nb<2;nb++)
        oacc[m][nb] = __builtin_amdgcn_mfma_f32_16x16x32_bf16(pf, vf[kb][nb].b, oacc[m][nb], 0,0,0);
    }
  }

  ushort_t* orow = o + (size_t)bw*64*512 + head*32;
  #pragma unroll
  for (int m=0;m<4;m++)
    #pragma unroll
    for (int nb=0;nb<2;nb++)
      #pragma unroll
      for (int r=0;r<4;r++){
        int i = m*16 + lk*4 + r;
        int d = nb*16 + lr;
        orow[(size_t)i*512 + d] = f2bf(oacc[m][nb][r]);
      }
}

// ---------------- launch ----------------
extern "C" void kernel_launch(void* const* d_in, const int* in_sizes, int n_in,
                              void* d_out, int out_size, void* d_ws, size_t ws_size,
                              hipStream_t stream) {
  const float* x      = (const float*)d_in[0];
  const float* n1g    = (const float*)d_in[1];
  const float* n1b    = (const float*)d_in[2];
  const float* qkv_w  = (const float*)d_in[3];
  const float* qkv_b  = (const float*)d_in[4];
  const float* rpb    = (const float*)d_in[5];
  const float* proj_w = (const float*)d_in[6];
  const float* proj_b = (const float*)d_in[7];
  const float* n2g    = (const float*)d_in[8];
  const float* n2b    = (const float*)d_in[9];
  const float* fc1_w  = (const float*)d_in[10];
  const float* fc1_b  = (const float*)d_in[11];
  const float* fc2_w  = (const float*)d_in[12];
  const float* fc2_b  = (const float*)d_in[13];
  float* out = (float*)d_out;

  ushort_t* ws = (ushort_t*)d_ws;
  size_t off = 0;
  ushort_t* wqT = ws + off; off += (size_t)1536*512;
  ushort_t* wpT = ws + off; off += (size_t)512*512;
  ushort_t* w1T = ws + off; off += (size_t)2048*512;
  ushort_t* w2T = ws + off; off += (size_t)512*2048;
  ushort_t* R1  = ws + off; off += (size_t)32768*512;   // hwin -> owin -> ln2out
  ushort_t* R2  = ws + off; off += (size_t)32768*2048;  // qkv -> fc1out
  if (ws_size < off*sizeof(ushort_t)) return;           // workspace too small: fail cleanly

  transpose_all<<<3072, dim3(32,8), 0, stream>>>(qkv_w, proj_w, fc1_w, fc2_w, wqT, wpT, w1T, w2T);

  ln_kernel<<<8192, 256, 0, stream>>>(x, n1g, n1b, R1, 1);
  gemm256<0><<<768, 512, 0, stream>>>(R1, wqT, qkv_b, R2, nullptr, 32768, 1536, 512, 6);
  attn_kernel<<<2048, 256, 0, stream>>>(R2, rpb, R1);
  gemm256<2><<<256, 512, 0, stream>>>(R1, wpT, proj_b, out, x, 32768, 512, 512, 2);
  ln_kernel<<<8192, 256, 0, stream>>>(out, n2g, n2b, R1, 0);
  gemmv<1><<<2048, 512, 0, stream>>>(R1, w1T, fc1_b, R2, nullptr, 32768, 2048, 512, 16);
  gemm256<3><<<256, 512, 0, stream>>>(R2, w2T, fc2_b, out, nullptr, 32768, 512, 2048, 2);
}